// Round 2
// baseline (76.925 us; speedup 1.0000x reference)
//
#include <hip/hip_runtime.h>
#include <math.h>

#define NB 8
#define NT 250
#define NK 64
#define NS 64000
#define BLOCKS_PER_B 251   // head + 249 interior segments + tail

#define MIDI_MAX 119.21309485364912f
#define LOG_EXP 2.302585092994046f     // np.float32(log(10))
#define INV_SR  (1.0f / 16000.0f)      // omega/2pi = freq / sample_rate (revolutions/sample)

__device__ __forceinline__ float wrev_from_x(float x) {
    // frequencies_sigmoid (depth=1, hz in [0,8000]) -> revolutions/sample
    float unit = 1.0f / (1.0f + expf(-x));
    float midi = MIDI_MAX * unit;
    return 440.0f * exp2f((midi - 69.0f) * (1.0f / 12.0f)) * INV_SR;
}

__device__ __forceinline__ float freq_from_x(float x) {
    float unit = 1.0f / (1.0f + expf(-x));
    float midi = MIDI_MAX * unit;
    return 440.0f * exp2f((midi - 69.0f) * (1.0f / 12.0f));
}

// Kernel 1: per (b,k), blocked scan of segment-boundary phases (revolutions).
// Bred[b][j][k] = (phase before interior segment j) mod 1, in [-0.5,0.5].
// d_j = 128*(w_{j-1}+w_j) with w_{-1}=0; B_j = sum_{i<=j} d_i.
__global__ __launch_bounds__(512) void sinsynth_setup(
        const float* __restrict__ freqs_in, float* __restrict__ Bred) {
    __shared__ float sw[NT * NK];      // 62.5 KB, revolutions/sample
    __shared__ double spart[8][NK];    // 4 KB chunk partial sums

    int b = blockIdx.x;
    int tid = threadIdx.x;
    const float* fp = freqs_in + (size_t)b * NT * NK;

    for (int idx = tid; idx < NT * NK; idx += 512)
        sw[idx] = wrev_from_x(fp[idx]);
    __syncthreads();

    int g = tid >> 6, k = tid & 63;
    int j0 = (NT * g) >> 3;            // chunk bounds: floor(250*g/8)
    int j1 = (NT * (g + 1)) >> 3;

    double S = 0.0;
    for (int j = j0; j < j1; ++j) {
        float wp = (j == 0) ? 0.0f : sw[(j - 1) * NK + k];
        S += 128.0 * ((double)wp + (double)sw[j * NK + k]);
    }
    spart[g][k] = S;
    __syncthreads();

    double B = 0.0;
    for (int gg = 0; gg < g; ++gg) B += spart[gg][k];

    float* Bp = Bred + (size_t)b * NT * NK + k;
    for (int j = j0; j < j1; ++j) {
        float wp = (j == 0) ? 0.0f : sw[(j - 1) * NK + k];
        B += 128.0 * ((double)wp + (double)sw[j * NK + k]);
        Bp[(size_t)j * NK] = (float)(B - rint(B));   // mod 1, revolutions
    }
}

// Kernel 2: one block per (b, region). region 0 = head (128 samples),
// 1..249 = interior segments (256 samples), 250 = tail (128 samples).
__global__ __launch_bounds__(256) void sinsynth_main(
        const float* __restrict__ amps_in, const float* __restrict__ freqs_in,
        const float* __restrict__ Bred, float* __restrict__ out) {
    __shared__ float4 sctl[NK];  // (w_j, dw, a_j, da) — w in rev/sample
    __shared__ float sB[NK];     // boundary phase, revolutions mod 1

    int blk = blockIdx.x;
    int b = blk / BLOCKS_PER_B;
    int t = blk - b * BLOCKS_PER_B;
    bool head = (t == 0);
    bool tail = (t == BLOCKS_PER_B - 1);
    int j  = head ? 0 : (t - 1);
    int j1 = (head || tail) ? j : (j + 1);

    int tid = threadIdx.x;
    int q = tid >> 6;           // wave-uniform role
    int k = tid & 63;
    int jj = (q & 1) ? j1 : j;
    size_t base = (size_t)(b * NT + jj) * NK + k;

    if (q < 2) {
        float w = wrev_from_x(freqs_in[base]);
        if (q == 0) {
            sctl[k].x = w;
            sB[k] = head ? 0.0f : Bred[(size_t)(b * NT + j) * NK + k];
        } else {
            sctl[k].y = w;
        }
    } else {
        float f = freq_from_x(freqs_in[base]);
        float xa = amps_in[base];
        float sig = 1.0f / (1.0f + expf(-xa));
        float amp = 2.0f * exp2f(LOG_EXP * log2f(sig)) + 1e-7f;  // exp_sigmoid
        if (f >= 8000.0f) amp = 0.0f;                            // nyquist mask
        if (q == 2) sctl[k].z = amp;
        else        sctl[k].w = amp;
    }
    __syncthreads();
    if (tid < NK) {            // convert to (value, delta) form
        sctl[tid].y -= sctl[tid].x;
        sctl[tid].w -= sctl[tid].z;
    }
    __syncthreads();

    bool active = (head || tail) ? (tid < 128) : true;
    if (active) {
        float n    = (float)(tid + 1);                  // samples into region
        float n2s  = n * n * (1.0f / 512.0f);
        float frac = (float)(2 * tid + 1) * (1.0f / 512.0f);
        float acc = 0.0f;
#pragma unroll 8
        for (int kk = 0; kk < NK; ++kk) {
            float4 c = sctl[kk];
            float tt  = fmaf(n2s, c.y, fmaf(n, c.x, sB[kk]));  // revolutions
            float amp = fmaf(frac, c.w, c.z);
            tt -= rintf(tt);                                   // [-0.5, 0.5]
            acc = fmaf(amp, __builtin_amdgcn_sinf(tt), acc);
        }
        int i = head ? tid : (tail ? (63872 + tid) : (256 * j + 128 + tid));
        out[(size_t)b * NS + i] = acc;
    }
}

extern "C" void kernel_launch(void* const* d_in, const int* in_sizes, int n_in,
                              void* d_out, int out_size, void* d_ws, size_t ws_size,
                              hipStream_t stream) {
    const float* amps  = (const float*)d_in[0];   // amplitudes [8,250,64]
    const float* freqs = (const float*)d_in[1];   // frequencies [8,250,64]
    float* out  = (float*)d_out;                  // [8,64000]
    float* Bred = (float*)d_ws;                   // 8*250*64 floats = 512 KB

    sinsynth_setup<<<NB, 512, 0, stream>>>(freqs, Bred);
    sinsynth_main<<<NB * BLOCKS_PER_B, 256, 0, stream>>>(amps, freqs, Bred, out);
}